// Round 3
// baseline (361.673 us; speedup 1.0000x reference)
//
#include <hip/hip_runtime.h>

#define N 8192
#define D 128
#define NT 64   // 128-row tiles per dimension
// zbf is prescaled by sqrt(2*log2(e)) so MFMA output = sim * 2*log2(e),
// i.e. exp(sim/T) == exp2(acc) directly (T = 0.5).
#define PRESCALE 1.6986435984699773f

typedef __bf16 bf16;
typedef __bf16 bf16x8 __attribute__((ext_vector_type(8)));
typedef float f32x4 __attribute__((ext_vector_type(4)));

// workspace layout
#define ZBF_OFF 0                    // N*D bf16 = 2 MB
#define DEN_OFF (N * D * 2)          // N fp32 = 32 KB
#define S_OFF   (DEN_OFF + N * 4)    // 128 fp32
#define SP_OFF  (S_OFF + 512)        // 128 fp32

// ---------------------------------------------------------------------------
// Kernel 1: row-normalize. 16-lane groups: wave = 4 row-groups of 16 lanes,
// lane g covers cols g*8..g*8+7 (two float4 loads). 4-deep shuffle reduce for
// the norm, 2-deep cross-q reduce for the column sums, LDS combine, one
// coalesced atomic pass. Writes zbf = z(eps1e-8) * PRESCALE.
// blocks [0,512) -> nodes, [512,1024) -> pair_nodes, 16 rows/block.
// ---------------------------------------------------------------------------
__global__ __launch_bounds__(256) void norm_kernel(
    const float* __restrict__ nodes, const float* __restrict__ pair,
    bf16* __restrict__ zbf, float* __restrict__ svec, float* __restrict__ spvec)
{
    __shared__ float red[4][128];
    const int tid = threadIdx.x;
    const int lane = tid & 63, wave = tid >> 6;
    const int g = lane & 15, q = lane >> 4;
    const bool isPair = blockIdx.x >= 512;
    const float* src = isPair ? pair : nodes;
    const int row = (blockIdx.x & 511) * 16 + wave * 4 + q;

    const float4 x0 = *(const float4*)(src + row * D + g * 8);
    const float4 x1 = *(const float4*)(src + row * D + g * 8 + 4);
    float ss = x0.x * x0.x + x0.y * x0.y + x0.z * x0.z + x0.w * x0.w
             + x1.x * x1.x + x1.y * x1.y + x1.z * x1.z + x1.w * x1.w;
    #pragma unroll
    for (int m = 1; m <= 8; m <<= 1) ss += __shfl_xor(ss, m, 64);
    const float nrm = sqrtf(ss);
    const float inv12 = 1.f / fmaxf(nrm, 1e-12f);

    // column-sum contribution (eps = 1e-12 per reference)
    float a[8] = { x0.x * inv12, x0.y * inv12, x0.z * inv12, x0.w * inv12,
                   x1.x * inv12, x1.y * inv12, x1.z * inv12, x1.w * inv12 };

    if (!isPair) {
        const float sc = PRESCALE / fmaxf(nrm, 1e-8f);
        bf16x8 pk;
        pk[0] = (bf16)(x0.x * sc); pk[1] = (bf16)(x0.y * sc);
        pk[2] = (bf16)(x0.z * sc); pk[3] = (bf16)(x0.w * sc);
        pk[4] = (bf16)(x1.x * sc); pk[5] = (bf16)(x1.y * sc);
        pk[6] = (bf16)(x1.z * sc); pk[7] = (bf16)(x1.w * sc);
        *(bf16x8*)(zbf + row * D + g * 8) = pk;
    }

    // reduce over the 4 rows (q) within the wave: xor 16, 32
    #pragma unroll
    for (int k = 0; k < 8; ++k) {
        a[k] += __shfl_xor(a[k], 16, 64);
        a[k] += __shfl_xor(a[k], 32, 64);
    }
    if (q == 0) {
        #pragma unroll
        for (int k = 0; k < 8; ++k) red[wave][g * 8 + k] = a[k];
    }
    __syncthreads();
    if (tid < 128) {
        float* dst = isPair ? spvec : svec;
        atomicAdd(&dst[tid], red[0][tid] + red[1][tid] + red[2][tid] + red[3][tid]);
    }
}

// ---------------------------------------------------------------------------
// Kernel 2: fused symmetric SYRK + exp + row/col sums, upper triangle only.
// 2080 blocks (ti <= tj), 128x128 tile, 4 waves (2x2 of 64x64),
// mfma_f32_16x16x32_bf16, K=128 as 2 x BK=64 LDS stages, LDP=80 pad
// (8 lanes per 4-bank group = b128 floor). Pipelined: kh1 global loads
// issue right after kh0's LDS writes, so their latency hides behind kh0
// compute. 4 barriers/block (was 5). Epilogue: e = exp2(acc) (prescaled),
// exact diag mask, shuffle + LDS combine, one coalesced atomic pass.
// ---------------------------------------------------------------------------
#define LDP 80

__global__ __launch_bounds__(256) void gemm_kernel(
    const bf16* __restrict__ zbf, float* __restrict__ den)
{
    __shared__ bf16 As[128 * LDP];
    __shared__ bf16 Bs[128 * LDP];
    __shared__ float rowacc[128];
    __shared__ float colacc[128];

    // decode upper-tri pair: offset(ti) = ti*(2*NT+1-ti)/2
    int b = blockIdx.x;
    int ti = (int)((2.0 * NT + 1.0 - sqrt((2.0 * NT + 1.0) * (2.0 * NT + 1.0) - 8.0 * (double)b)) * 0.5);
    while (ti > 0 && ti * (2 * NT + 1 - ti) / 2 > b) --ti;
    while ((ti + 1) * (2 * NT - ti) / 2 <= b) ++ti;
    const int tj = ti + (b - ti * (2 * NT + 1 - ti) / 2);
    const bool diag = (ti == tj);

    const int tid  = threadIdx.x;
    const int lane = tid & 63, wave = tid >> 6;
    const int wm = wave >> 1, wn = wave & 1;
    const int quad = lane >> 4, c = lane & 15;
    const int ibase = ti * 128;   // rows (As)
    const int jbase = tj * 128;   // cols (Bs)

    if (tid < 128) { rowacc[tid] = 0.f; colacc[tid] = 0.f; }

    f32x4 acc[4][4];
    #pragma unroll
    for (int i = 0; i < 4; ++i)
        #pragma unroll
        for (int j = 0; j < 4; ++j) acc[i][j] = (f32x4){0.f, 0.f, 0.f, 0.f};

    // staging addresses: chunk = tid + 256*i, row = chunk>>3, c8 = (chunk&7)*8
    // ---- kh0: load + write ----
    uint4 va[4], vb[4];
    #pragma unroll
    for (int i = 0; i < 4; ++i) {
        const int chunk = tid + 256 * i;
        const int row = chunk >> 3, c8 = (chunk & 7) * 8;
        va[i] = *(const uint4*)(zbf + (ibase + row) * D + c8);
        vb[i] = *(const uint4*)(zbf + (jbase + row) * D + c8);
    }
    #pragma unroll
    for (int i = 0; i < 4; ++i) {
        const int chunk = tid + 256 * i;
        const int row = chunk >> 3, c8 = (chunk & 7) * 8;
        *(uint4*)(&As[row * LDP + c8]) = va[i];
        *(uint4*)(&Bs[row * LDP + c8]) = vb[i];
    }
    // ---- kh1: issue loads now; latency hides behind kh0 compute ----
    #pragma unroll
    for (int i = 0; i < 4; ++i) {
        const int chunk = tid + 256 * i;
        const int row = chunk >> 3, c8 = (chunk & 7) * 8;
        va[i] = *(const uint4*)(zbf + (ibase + row) * D + 64 + c8);
        vb[i] = *(const uint4*)(zbf + (jbase + row) * D + 64 + c8);
    }
    __syncthreads();

    #pragma unroll
    for (int kh = 0; kh < 2; ++kh) {
        #pragma unroll
        for (int ks = 0; ks < 2; ++ks) {
            const int kk = ks * 32;
            bf16x8 af[4], bfr[4];
            #pragma unroll
            for (int mi = 0; mi < 4; ++mi)
                af[mi] = *(const bf16x8*)(&As[(wm * 64 + mi * 16 + c) * LDP + kk + quad * 8]);
            #pragma unroll
            for (int ni = 0; ni < 4; ++ni)
                bfr[ni] = *(const bf16x8*)(&Bs[(wn * 64 + ni * 16 + c) * LDP + kk + quad * 8]);
            #pragma unroll
            for (int mi = 0; mi < 4; ++mi)
                #pragma unroll
                for (int ni = 0; ni < 4; ++ni)
                    acc[mi][ni] = __builtin_amdgcn_mfma_f32_16x16x32_bf16(
                        af[mi], bfr[ni], acc[mi][ni], 0, 0, 0);
        }
        if (kh == 0) {
            __syncthreads();  // all kh0 reads done before overwrite
            #pragma unroll
            for (int i = 0; i < 4; ++i) {
                const int chunk = tid + 256 * i;
                const int row = chunk >> 3, c8 = (chunk & 7) * 8;
                *(uint4*)(&As[row * LDP + c8]) = va[i];
                *(uint4*)(&Bs[row * LDP + c8]) = vb[i];
            }
            __syncthreads();
        }
    }

    // ---- epilogue: exp + masked row/col partial sums ----------------------
    float rowp[4][4];
    float colp[4];
    #pragma unroll
    for (int mi = 0; mi < 4; ++mi)
        #pragma unroll
        for (int r = 0; r < 4; ++r) rowp[mi][r] = 0.f;
    #pragma unroll
    for (int ni = 0; ni < 4; ++ni) colp[ni] = 0.f;

    #pragma unroll
    for (int mi = 0; mi < 4; ++mi) {
        const int lrow0 = wm * 64 + mi * 16 + quad * 4;
        #pragma unroll
        for (int ni = 0; ni < 4; ++ni) {
            const int lcol = wn * 64 + ni * 16 + c;
            const f32x4 cv = acc[mi][ni];
            #pragma unroll
            for (int r = 0; r < 4; ++r) {
                float e = __builtin_amdgcn_exp2f(cv[r]);  // prescaled: acc = sim/T*log2(e)... = 2log2e*sim
                if (diag && (lrow0 + r == lcol)) e = 0.f;  // exact self-mask
                rowp[mi][r] += e;
                colp[ni]    += e;
            }
        }
    }

    // rowsum: reduce over the 16 column-lanes (bits 0..3)
    #pragma unroll
    for (int mi = 0; mi < 4; ++mi)
        #pragma unroll
        for (int r = 0; r < 4; ++r) {
            #pragma unroll
            for (int m = 1; m <= 8; m <<= 1)
                rowp[mi][r] += __shfl_xor(rowp[mi][r], m, 64);
        }
    if (c == 0) {
        #pragma unroll
        for (int mi = 0; mi < 4; ++mi)
            #pragma unroll
            for (int r = 0; r < 4; ++r)
                atomicAdd(&rowacc[wm * 64 + mi * 16 + quad * 4 + r], rowp[mi][r]);
    }

    if (!diag) {
        // colsum: reduce over the 4 quads (bits 4..5)
        #pragma unroll
        for (int ni = 0; ni < 4; ++ni) {
            colp[ni] += __shfl_xor(colp[ni], 16, 64);
            colp[ni] += __shfl_xor(colp[ni], 32, 64);
        }
        if (quad == 0) {
            #pragma unroll
            for (int ni = 0; ni < 4; ++ni)
                atomicAdd(&colacc[wn * 64 + ni * 16 + c], colp[ni]);
        }
    }

    __syncthreads();
    if (tid < 128) {
        atomicAdd(&den[ibase + tid], rowacc[tid]);
        if (!diag) atomicAdd(&den[jbase + tid], colacc[tid]);
    }
}

// ---------------------------------------------------------------------------
// Kernel 3: loss = sum_j log(den[j]) - dot(s, sp)/(T*N)
// ---------------------------------------------------------------------------
__global__ __launch_bounds__(256) void final_kernel(
    const float* __restrict__ den, const float* __restrict__ s,
    const float* __restrict__ sp, float* __restrict__ out)
{
    __shared__ float red[4];
    const int tid = threadIdx.x;
    float v = 0.f;
    for (int j = tid; j < N; j += 256) v += logf(den[j]);
    if (tid < 128) v -= s[tid] * sp[tid] * (1.f / 4096.f);  // 1/(T*N)
    #pragma unroll
    for (int m = 32; m >= 1; m >>= 1) v += __shfl_xor(v, m, 64);
    if ((tid & 63) == 0) red[tid >> 6] = v;
    __syncthreads();
    if (tid == 0) out[0] = red[0] + red[1] + red[2] + red[3];
}

extern "C" void kernel_launch(void* const* d_in, const int* in_sizes, int n_in,
                              void* d_out, int out_size, void* d_ws, size_t ws_size,
                              hipStream_t stream)
{
    const float* nodes = (const float*)d_in[0];
    const float* pair  = (const float*)d_in[1];
    // d_in[2] (labels) and d_in[3] (mask = eye(N)) are unused: labels don't
    // enter the loss; the self-mask is applied exactly in-kernel.

    char*  ws  = (char*)d_ws;
    bf16*  zbf = (bf16*)(ws + ZBF_OFF);
    float* den = (float*)(ws + DEN_OFF);
    float* s   = (float*)(ws + S_OFF);
    float* sp  = (float*)(ws + SP_OFF);

    // zero den + s + sp (ws is poisoned 0xAA before every timed call)
    hipMemsetAsync(ws + DEN_OFF, 0, N * 4 + 1024, stream);

    hipLaunchKernelGGL(norm_kernel, dim3(1024), dim3(256), 0, stream,
                       nodes, pair, zbf, s, sp);
    hipLaunchKernelGGL(gemm_kernel, dim3(NT * (NT + 1) / 2), dim3(256), 0, stream,
                       zbf, den);
    hipLaunchKernelGGL(final_kernel, dim3(1), dim3(256), 0, stream,
                       den, s, sp, (float*)d_out);
}

// Round 4
// 339.900 us; speedup vs baseline: 1.0641x; 1.0641x over previous
//
#include <hip/hip_runtime.h>

#define N 8192
#define D 128
#define NT 64   // 128-row tiles per dimension
// zbf is prescaled by sqrt(2*log2(e)) so MFMA output = sim * 2*log2(e),
// i.e. exp(sim/T) == exp2(acc) directly (T = 0.5).
#define PRESCALE 1.6986435984699773f

typedef __bf16 bf16;
typedef __bf16 bf16x8 __attribute__((ext_vector_type(8)));
typedef float f32x4 __attribute__((ext_vector_type(4)));

// workspace layout
#define ZBF_OFF 0                    // N*D bf16 = 2 MB
#define DEN_OFF (N * D * 2)          // N fp32 = 32 KB
#define S_OFF   (DEN_OFF + N * 4)    // 128 fp32
#define SP_OFF  (S_OFF + 512)        // 128 fp32

// async global->LDS, 16B per lane. LDS dest is wave-uniform base + lane*16.
__device__ __forceinline__ void load_lds16(const bf16* g, bf16* l) {
    __builtin_amdgcn_global_load_lds(
        (const __attribute__((address_space(1))) unsigned int*)g,
        (__attribute__((address_space(3))) unsigned int*)l, 16, 0, 0);
}

// ---------------------------------------------------------------------------
// Kernel 1: row-normalize (one 16-lane group per row chunk; 4 rows/wave).
// Writes zbf = z(eps=1e-8) * PRESCALE; accumulates column sums of
// z(eps=1e-12) for nodes (svec) and pair_nodes (spvec).
// blocks [0,512) -> nodes, [512,1024) -> pair_nodes, 16 rows/block.
// ---------------------------------------------------------------------------
__global__ __launch_bounds__(256) void norm_kernel(
    const float* __restrict__ nodes, const float* __restrict__ pair,
    bf16* __restrict__ zbf, float* __restrict__ svec, float* __restrict__ spvec)
{
    __shared__ float red[4][128];
    const int tid = threadIdx.x;
    const int lane = tid & 63, wave = tid >> 6;
    const int g = lane & 15, q = lane >> 4;
    const bool isPair = blockIdx.x >= 512;
    const float* src = isPair ? pair : nodes;
    const int row = (blockIdx.x & 511) * 16 + wave * 4 + q;

    const float4 x0 = *(const float4*)(src + row * D + g * 8);
    const float4 x1 = *(const float4*)(src + row * D + g * 8 + 4);
    float ss = x0.x * x0.x + x0.y * x0.y + x0.z * x0.z + x0.w * x0.w
             + x1.x * x1.x + x1.y * x1.y + x1.z * x1.z + x1.w * x1.w;
    #pragma unroll
    for (int m = 1; m <= 8; m <<= 1) ss += __shfl_xor(ss, m, 64);
    const float nrm = sqrtf(ss);
    const float inv12 = 1.f / fmaxf(nrm, 1e-12f);

    float a[8] = { x0.x * inv12, x0.y * inv12, x0.z * inv12, x0.w * inv12,
                   x1.x * inv12, x1.y * inv12, x1.z * inv12, x1.w * inv12 };

    if (!isPair) {
        const float sc = PRESCALE / fmaxf(nrm, 1e-8f);
        bf16x8 pk;
        pk[0] = (bf16)(x0.x * sc); pk[1] = (bf16)(x0.y * sc);
        pk[2] = (bf16)(x0.z * sc); pk[3] = (bf16)(x0.w * sc);
        pk[4] = (bf16)(x1.x * sc); pk[5] = (bf16)(x1.y * sc);
        pk[6] = (bf16)(x1.z * sc); pk[7] = (bf16)(x1.w * sc);
        *(bf16x8*)(zbf + row * D + g * 8) = pk;
    }

    #pragma unroll
    for (int k = 0; k < 8; ++k) {
        a[k] += __shfl_xor(a[k], 16, 64);
        a[k] += __shfl_xor(a[k], 32, 64);
    }
    if (q == 0) {
        #pragma unroll
        for (int k = 0; k < 8; ++k) red[wave][g * 8 + k] = a[k];
    }
    __syncthreads();
    if (tid < 128) {
        float* dst = isPair ? spvec : svec;
        atomicAdd(&dst[tid], red[0][tid] + red[1][tid] + red[2][tid] + red[3][tid]);
    }
}

// ---------------------------------------------------------------------------
// Kernel 2: fused symmetric SYRK + exp + row/col sums, upper triangle only.
// 2080 blocks (ti <= tj), 128x128 tile, 4 waves (2x2 of 64x64),
// mfma_f32_16x16x32_bf16, FULL K=128 staged once via async
// global_load_lds width=16 (no staging VGPRs, no ds_writes, 2 barriers).
// LDS is unpadded (row stride 256B — required by load_lds); bank conflicts
// broken by XOR swizzle on the GLOBAL source address: slot cc of row r
// holds global chunk cc ^ (r&15). Frag read at chunk s for row r reads
// slot (s ^ (r&15)) -> 8 lanes per 4-bank group = b128 floor, conflict-free.
// Diag tiles skip B staging (frags alias As). Epilogue: e = exp2(acc)
// (prescaled), exact diag mask, shuffle reduce, plain disjoint LDS stores
// (rowacc[wn], colacc[wm] — no atomics, no init), one coalesced global
// atomic pass.
// ---------------------------------------------------------------------------
__global__ __launch_bounds__(256) void gemm_kernel(
    const bf16* __restrict__ zbf, float* __restrict__ den)
{
    __shared__ bf16 As[128 * 128];
    __shared__ bf16 Bs[128 * 128];
    __shared__ float rowacc[2][128];
    __shared__ float colacc[2][128];

    // decode upper-tri pair: offset(ti) = ti*(2*NT+1-ti)/2
    int b = blockIdx.x;
    int ti = (int)((2.0 * NT + 1.0 - sqrt((2.0 * NT + 1.0) * (2.0 * NT + 1.0) - 8.0 * (double)b)) * 0.5);
    while (ti > 0 && ti * (2 * NT + 1 - ti) / 2 > b) --ti;
    while ((ti + 1) * (2 * NT - ti) / 2 <= b) ++ti;
    const int tj = ti + (b - ti * (2 * NT + 1 - ti) / 2);
    const bool diag = (ti == tj);

    const int tid  = threadIdx.x;
    const int lane = tid & 63, wave = tid >> 6;
    const int wm = wave >> 1, wn = wave & 1;
    const int quad = lane >> 4, c = lane & 15;
    const int ibase = ti * 128;   // rows (As)
    const int jbase = tj * 128;   // cols (Bs)

    // ---- async stage: each wave call = 1024B LDS = 4 rows of 256B --------
    // call i of wave w covers rows [ (w*8+i)*4, +4 ); lane l -> row +l/16,
    // slot l%16, global chunk (l%16) ^ (row&15).
    {
        const int rsub = lane >> 4;          // 0..3 row within call
        const int slot = lane & 15;          // 16B slot within row
        #pragma unroll
        for (int i = 0; i < 8; ++i) {
            const int blk4 = wave * 8 + i;
            const int row  = blk4 * 4 + rsub;
            const int cc   = slot ^ (row & 15);
            load_lds16(zbf + (ibase + row) * D + cc * 8, As + blk4 * 512 + lane * 8);
        }
        if (!diag) {
            #pragma unroll
            for (int i = 0; i < 8; ++i) {
                const int blk4 = wave * 8 + i;
                const int row  = blk4 * 4 + rsub;
                const int cc   = slot ^ (row & 15);
                load_lds16(zbf + (jbase + row) * D + cc * 8, Bs + blk4 * 512 + lane * 8);
            }
        }
    }
    __syncthreads();  // vmcnt(0) drain + barrier: LDS tiles complete

    const bf16* Bp = diag ? As : Bs;

    f32x4 acc[4][4];
    #pragma unroll
    for (int i = 0; i < 4; ++i)
        #pragma unroll
        for (int j = 0; j < 4; ++j) acc[i][j] = (f32x4){0.f, 0.f, 0.f, 0.f};

    #pragma unroll
    for (int ks = 0; ks < 4; ++ks) {
        const int s = ks * 4 + quad;          // global 8-chunk index 0..15
        bf16x8 af[4], bfr[4];
        #pragma unroll
        for (int mi = 0; mi < 4; ++mi) {
            const int r = wm * 64 + mi * 16 + c;      // r&15 == c
            af[mi] = *(const bf16x8*)(As + r * 128 + ((s ^ c) * 8));
        }
        #pragma unroll
        for (int ni = 0; ni < 4; ++ni) {
            const int r = wn * 64 + ni * 16 + c;
            bfr[ni] = *(const bf16x8*)(Bp + r * 128 + ((s ^ c) * 8));
        }
        #pragma unroll
        for (int mi = 0; mi < 4; ++mi)
            #pragma unroll
            for (int ni = 0; ni < 4; ++ni)
                acc[mi][ni] = __builtin_amdgcn_mfma_f32_16x16x32_bf16(
                    af[mi], bfr[ni], acc[mi][ni], 0, 0, 0);
    }

    // ---- epilogue: exp + masked row/col partial sums ----------------------
    float rowp[4][4];
    float colp[4];
    #pragma unroll
    for (int mi = 0; mi < 4; ++mi)
        #pragma unroll
        for (int r = 0; r < 4; ++r) rowp[mi][r] = 0.f;
    #pragma unroll
    for (int ni = 0; ni < 4; ++ni) colp[ni] = 0.f;

    #pragma unroll
    for (int mi = 0; mi < 4; ++mi) {
        const int lrow0 = wm * 64 + mi * 16 + quad * 4;
        #pragma unroll
        for (int ni = 0; ni < 4; ++ni) {
            const int lcol = wn * 64 + ni * 16 + c;
            const f32x4 cv = acc[mi][ni];
            #pragma unroll
            for (int r = 0; r < 4; ++r) {
                float e = __builtin_amdgcn_exp2f(cv[r]);   // prescaled input
                if (diag && (lrow0 + r == lcol)) e = 0.f;  // exact self-mask
                rowp[mi][r] += e;
                colp[ni]    += e;
            }
        }
    }

    // rowsum: reduce over the 16 column-lanes (bits 0..3)
    #pragma unroll
    for (int mi = 0; mi < 4; ++mi)
        #pragma unroll
        for (int r = 0; r < 4; ++r) {
            #pragma unroll
            for (int m = 1; m <= 8; m <<= 1)
                rowp[mi][r] += __shfl_xor(rowp[mi][r], m, 64);
        }
    if (c == 0) {
        // disjoint per (wn, row): plain stores, no atomics, no init needed
        #pragma unroll
        for (int mi = 0; mi < 4; ++mi)
            #pragma unroll
            for (int r = 0; r < 4; ++r)
                rowacc[wn][wm * 64 + mi * 16 + quad * 4 + r] = rowp[mi][r];
    }

    if (!diag) {
        // colsum: reduce over the 4 quads (bits 4..5)
        #pragma unroll
        for (int ni = 0; ni < 4; ++ni) {
            colp[ni] += __shfl_xor(colp[ni], 16, 64);
            colp[ni] += __shfl_xor(colp[ni], 32, 64);
        }
        if (quad == 0) {
            #pragma unroll
            for (int ni = 0; ni < 4; ++ni)
                colacc[wm][wn * 64 + ni * 16 + c] = colp[ni];
        }
    }

    __syncthreads();
    if (tid < 128) {
        atomicAdd(&den[ibase + tid], rowacc[0][tid] + rowacc[1][tid]);
        if (!diag) atomicAdd(&den[jbase + tid], colacc[0][tid] + colacc[1][tid]);
    }
}

// ---------------------------------------------------------------------------
// Kernel 3: loss = sum_j log(den[j]) - dot(s, sp)/(T*N).
// 16 blocks x 512 den entries; block 0 adds the dot term; atomicAdd to out
// (out zeroed via 4B memset in kernel_launch).
// ---------------------------------------------------------------------------
__global__ __launch_bounds__(256) void final_kernel(
    const float* __restrict__ den, const float* __restrict__ s,
    const float* __restrict__ sp, float* __restrict__ out)
{
    __shared__ float red[4];
    const int tid = threadIdx.x, lane = tid & 63, wave = tid >> 6;
    const float2 d2 = *(const float2*)(den + blockIdx.x * 512 + tid * 2);
    float v = logf(d2.x) + logf(d2.y);
    if (blockIdx.x == 0 && tid < 128)
        v -= s[tid] * sp[tid] * (1.f / 4096.f);  // 1/(T*N)
    #pragma unroll
    for (int m = 32; m >= 1; m >>= 1) v += __shfl_xor(v, m, 64);
    if (lane == 0) red[wave] = v;
    __syncthreads();
    if (tid == 0) atomicAdd(out, red[0] + red[1] + red[2] + red[3]);
}

extern "C" void kernel_launch(void* const* d_in, const int* in_sizes, int n_in,
                              void* d_out, int out_size, void* d_ws, size_t ws_size,
                              hipStream_t stream)
{
    const float* nodes = (const float*)d_in[0];
    const float* pair  = (const float*)d_in[1];
    // d_in[2] (labels) and d_in[3] (mask = eye(N)) are unused: labels don't
    // enter the loss; the self-mask is applied exactly in-kernel.

    char*  ws  = (char*)d_ws;
    bf16*  zbf = (bf16*)(ws + ZBF_OFF);
    float* den = (float*)(ws + DEN_OFF);
    float* s   = (float*)(ws + S_OFF);
    float* sp  = (float*)(ws + SP_OFF);

    // zero den + s + sp (ws is poisoned 0xAA before every timed call) and out
    hipMemsetAsync(ws + DEN_OFF, 0, N * 4 + 1024, stream);
    hipMemsetAsync(d_out, 0, 4, stream);

    hipLaunchKernelGGL(norm_kernel, dim3(1024), dim3(256), 0, stream,
                       nodes, pair, zbf, s, sp);
    hipLaunchKernelGGL(gemm_kernel, dim3(NT * (NT + 1) / 2), dim3(256), 0, stream,
                       zbf, den);
    hipLaunchKernelGGL(final_kernel, dim3(16), dim3(256), 0, stream,
                       den, s, sp, (float*)d_out);
}

// Round 5
// 334.020 us; speedup vs baseline: 1.0828x; 1.0176x over previous
//
#include <hip/hip_runtime.h>

#define N 8192
#define D 128
#define NT 64   // 128-row tiles per dimension
// zbf is prescaled by sqrt(2*log2(e)) so MFMA output = sim * 2*log2(e),
// i.e. exp(sim/T) == exp2(acc) directly (T = 0.5).
#define PRESCALE 1.6986435984699773f

typedef __bf16 bf16;
typedef __bf16 bf16x8 __attribute__((ext_vector_type(8)));
typedef float f32x4 __attribute__((ext_vector_type(4)));

// workspace layout
#define ZBF_OFF 0                    // N*D bf16 = 2 MB
#define DEN_OFF (N * D * 2)          // N fp32 = 32 KB
#define S_OFF   (DEN_OFF + N * 4)    // 128 fp32
#define SP_OFF  (S_OFF + 512)        // 128 fp32

// async global->LDS, 16B per lane. LDS dest is wave-uniform base + lane*16.
__device__ __forceinline__ void load_lds16(const bf16* g, bf16* l) {
    __builtin_amdgcn_global_load_lds(
        (const __attribute__((address_space(1))) unsigned int*)g,
        (__attribute__((address_space(3))) unsigned int*)l, 16, 0, 0);
}

// ---------------------------------------------------------------------------
// Kernel 1: row-normalize + workspace zeroing (replaces both memsets).
// 256 blocks: [0,128) -> nodes, [128,256) -> pair_nodes; 64 rows/block
// (each wave: 4 row-groups of 16 lanes x 4 iterations). Writes
// zbf = z(eps=1e-8)*PRESCALE; accumulates column sums of z(eps=1e-12);
// one atomic pass per block -> 128 contributions/address (4x less
// contention than R4). Blocks 0..31 also zero den; block 0 zeroes
// s/sp tail guard and out. Stream order makes the zeros visible to gemm.
// ---------------------------------------------------------------------------
__global__ __launch_bounds__(256) void norm_kernel(
    const float* __restrict__ nodes, const float* __restrict__ pair,
    bf16* __restrict__ zbf, float* __restrict__ svec, float* __restrict__ spvec,
    float* __restrict__ den, float* __restrict__ out)
{
    __shared__ float red[4][128];
    const int tid = threadIdx.x;
    const int lane = tid & 63, wave = tid >> 6;
    const int g = lane & 15, q = lane >> 4;
    const bool isPair = blockIdx.x >= 128;
    const float* src = isPair ? pair : nodes;
    const int rowbase = (blockIdx.x & 127) * 64 + wave * 16;

    // zero den (32KB) and out while loads are in flight
    if (blockIdx.x < 32) den[blockIdx.x * 256 + tid] = 0.f;
    if (blockIdx.x == 0 && tid == 0) out[0] = 0.f;

    float a[8] = {0.f, 0.f, 0.f, 0.f, 0.f, 0.f, 0.f, 0.f};

    #pragma unroll
    for (int it = 0; it < 4; ++it) {
        const int row = rowbase + it * 4 + q;
        const float4 x0 = *(const float4*)(src + row * D + g * 8);
        const float4 x1 = *(const float4*)(src + row * D + g * 8 + 4);
        float ss = x0.x * x0.x + x0.y * x0.y + x0.z * x0.z + x0.w * x0.w
                 + x1.x * x1.x + x1.y * x1.y + x1.z * x1.z + x1.w * x1.w;
        #pragma unroll
        for (int m = 1; m <= 8; m <<= 1) ss += __shfl_xor(ss, m, 64);
        const float nrm = sqrtf(ss);
        const float inv12 = 1.f / fmaxf(nrm, 1e-12f);

        a[0] += x0.x * inv12; a[1] += x0.y * inv12;
        a[2] += x0.z * inv12; a[3] += x0.w * inv12;
        a[4] += x1.x * inv12; a[5] += x1.y * inv12;
        a[6] += x1.z * inv12; a[7] += x1.w * inv12;

        if (!isPair) {
            const float sc = PRESCALE / fmaxf(nrm, 1e-8f);
            bf16x8 pk;
            pk[0] = (bf16)(x0.x * sc); pk[1] = (bf16)(x0.y * sc);
            pk[2] = (bf16)(x0.z * sc); pk[3] = (bf16)(x0.w * sc);
            pk[4] = (bf16)(x1.x * sc); pk[5] = (bf16)(x1.y * sc);
            pk[6] = (bf16)(x1.z * sc); pk[7] = (bf16)(x1.w * sc);
            *(bf16x8*)(zbf + row * D + g * 8) = pk;
        }
    }

    // reduce over the 4 row-slots (q) within the wave
    #pragma unroll
    for (int k = 0; k < 8; ++k) {
        a[k] += __shfl_xor(a[k], 16, 64);
        a[k] += __shfl_xor(a[k], 32, 64);
    }
    if (q == 0) {
        #pragma unroll
        for (int k = 0; k < 8; ++k) red[wave][g * 8 + k] = a[k];
    }
    __syncthreads();
    if (tid < 128) {
        float* dst = isPair ? spvec : svec;
        atomicAdd(&dst[tid], red[0][tid] + red[1][tid] + red[2][tid] + red[3][tid]);
    }
}

// ---------------------------------------------------------------------------
// Kernel 2: fused symmetric SYRK + exp + row/col sums, upper triangle only.
// (unchanged from R4 — the verified winner)
// 2080 blocks (ti <= tj), 128x128 tile, 4 waves (2x2 of 64x64),
// mfma_f32_16x16x32_bf16, FULL K=128 staged once via async
// global_load_lds width=16 (no staging VGPRs, no ds_writes, 2 barriers).
// Bank conflicts broken by XOR swizzle on the GLOBAL source address.
// ---------------------------------------------------------------------------
__global__ __launch_bounds__(256) void gemm_kernel(
    const bf16* __restrict__ zbf, float* __restrict__ den)
{
    __shared__ bf16 As[128 * 128];
    __shared__ bf16 Bs[128 * 128];
    __shared__ float rowacc[2][128];
    __shared__ float colacc[2][128];

    // decode upper-tri pair: offset(ti) = ti*(2*NT+1-ti)/2
    int b = blockIdx.x;
    int ti = (int)((2.0 * NT + 1.0 - sqrt((2.0 * NT + 1.0) * (2.0 * NT + 1.0) - 8.0 * (double)b)) * 0.5);
    while (ti > 0 && ti * (2 * NT + 1 - ti) / 2 > b) --ti;
    while ((ti + 1) * (2 * NT - ti) / 2 <= b) ++ti;
    const int tj = ti + (b - ti * (2 * NT + 1 - ti) / 2);
    const bool diag = (ti == tj);

    const int tid  = threadIdx.x;
    const int lane = tid & 63, wave = tid >> 6;
    const int wm = wave >> 1, wn = wave & 1;
    const int quad = lane >> 4, c = lane & 15;
    const int ibase = ti * 128;   // rows (As)
    const int jbase = tj * 128;   // cols (Bs)

    {
        const int rsub = lane >> 4;          // 0..3 row within call
        const int slot = lane & 15;          // 16B slot within row
        #pragma unroll
        for (int i = 0; i < 8; ++i) {
            const int blk4 = wave * 8 + i;
            const int row  = blk4 * 4 + rsub;
            const int cc   = slot ^ (row & 15);
            load_lds16(zbf + (ibase + row) * D + cc * 8, As + blk4 * 512 + lane * 8);
        }
        if (!diag) {
            #pragma unroll
            for (int i = 0; i < 8; ++i) {
                const int blk4 = wave * 8 + i;
                const int row  = blk4 * 4 + rsub;
                const int cc   = slot ^ (row & 15);
                load_lds16(zbf + (jbase + row) * D + cc * 8, Bs + blk4 * 512 + lane * 8);
            }
        }
    }
    __syncthreads();  // vmcnt(0) drain + barrier: LDS tiles complete

    const bf16* Bp = diag ? As : Bs;

    f32x4 acc[4][4];
    #pragma unroll
    for (int i = 0; i < 4; ++i)
        #pragma unroll
        for (int j = 0; j < 4; ++j) acc[i][j] = (f32x4){0.f, 0.f, 0.f, 0.f};

    #pragma unroll
    for (int ks = 0; ks < 4; ++ks) {
        const int s = ks * 4 + quad;          // global 8-chunk index 0..15
        bf16x8 af[4], bfr[4];
        #pragma unroll
        for (int mi = 0; mi < 4; ++mi) {
            const int r = wm * 64 + mi * 16 + c;      // r&15 == c
            af[mi] = *(const bf16x8*)(As + r * 128 + ((s ^ c) * 8));
        }
        #pragma unroll
        for (int ni = 0; ni < 4; ++ni) {
            const int r = wn * 64 + ni * 16 + c;
            bfr[ni] = *(const bf16x8*)(Bp + r * 128 + ((s ^ c) * 8));
        }
        #pragma unroll
        for (int mi = 0; mi < 4; ++mi)
            #pragma unroll
            for (int ni = 0; ni < 4; ++ni)
                acc[mi][ni] = __builtin_amdgcn_mfma_f32_16x16x32_bf16(
                    af[mi], bfr[ni], acc[mi][ni], 0, 0, 0);
    }

    // ---- epilogue: exp + masked row/col partial sums ----------------------
    float rowp[4][4];
    float colp[4];
    #pragma unroll
    for (int mi = 0; mi < 4; ++mi)
        #pragma unroll
        for (int r = 0; r < 4; ++r) rowp[mi][r] = 0.f;
    #pragma unroll
    for (int ni = 0; ni < 4; ++ni) colp[ni] = 0.f;

    #pragma unroll
    for (int mi = 0; mi < 4; ++mi) {
        const int lrow0 = wm * 64 + mi * 16 + quad * 4;
        #pragma unroll
        for (int ni = 0; ni < 4; ++ni) {
            const int lcol = wn * 64 + ni * 16 + c;
            const f32x4 cv = acc[mi][ni];
            #pragma unroll
            for (int r = 0; r < 4; ++r) {
                float e = __builtin_amdgcn_exp2f(cv[r]);   // prescaled input
                if (diag && (lrow0 + r == lcol)) e = 0.f;  // exact self-mask
                rowp[mi][r] += e;
                colp[ni]    += e;
            }
        }
    }

    // rowsum: reduce over the 16 column-lanes (bits 0..3)
    #pragma unroll
    for (int mi = 0; mi < 4; ++mi)
        #pragma unroll
        for (int r = 0; r < 4; ++r) {
            #pragma unroll
            for (int m = 1; m <= 8; m <<= 1)
                rowp[mi][r] += __shfl_xor(rowp[mi][r], m, 64);
        }
    if (c == 0) {
        #pragma unroll
        for (int mi = 0; mi < 4; ++mi)
            #pragma unroll
            for (int r = 0; r < 4; ++r)
                rowacc[wn][wm * 64 + mi * 16 + quad * 4 + r] = rowp[mi][r];
    }

    if (!diag) {
        // colsum: reduce over the 4 quads (bits 4..5)
        #pragma unroll
        for (int ni = 0; ni < 4; ++ni) {
            colp[ni] += __shfl_xor(colp[ni], 16, 64);
            colp[ni] += __shfl_xor(colp[ni], 32, 64);
        }
        if (quad == 0) {
            #pragma unroll
            for (int ni = 0; ni < 4; ++ni)
                colacc[wm][wn * 64 + ni * 16 + c] = colp[ni];
        }
    }

    __syncthreads();
    if (tid < 128) {
        atomicAdd(&den[ibase + tid], rowacc[0][tid] + rowacc[1][tid]);
        if (!diag) atomicAdd(&den[jbase + tid], colacc[0][tid] + colacc[1][tid]);
    }
}

// ---------------------------------------------------------------------------
// Kernel 3: loss = sum_j log(den[j]) - dot(s, sp)/(T*N).
// 16 blocks x 512 den entries; block 0 adds the dot term; atomicAdd to out
// (out zeroed by norm_kernel).
// ---------------------------------------------------------------------------
__global__ __launch_bounds__(256) void final_kernel(
    const float* __restrict__ den, const float* __restrict__ s,
    const float* __restrict__ sp, float* __restrict__ out)
{
    __shared__ float red[4];
    const int tid = threadIdx.x, lane = tid & 63, wave = tid >> 6;
    const float2 d2 = *(const float2*)(den + blockIdx.x * 512 + tid * 2);
    float v = logf(d2.x) + logf(d2.y);
    if (blockIdx.x == 0 && tid < 128)
        v -= s[tid] * sp[tid] * (1.f / 4096.f);  // 1/(T*N)
    #pragma unroll
    for (int m = 32; m >= 1; m >>= 1) v += __shfl_xor(v, m, 64);
    if (lane == 0) red[wave] = v;
    __syncthreads();
    if (tid == 0) atomicAdd(out, red[0] + red[1] + red[2] + red[3]);
}

extern "C" void kernel_launch(void* const* d_in, const int* in_sizes, int n_in,
                              void* d_out, int out_size, void* d_ws, size_t ws_size,
                              hipStream_t stream)
{
    const float* nodes = (const float*)d_in[0];
    const float* pair  = (const float*)d_in[1];
    // d_in[2] (labels) and d_in[3] (mask = eye(N)) are unused: labels don't
    // enter the loss; the self-mask is applied exactly in-kernel.

    char*  ws  = (char*)d_ws;
    bf16*  zbf = (bf16*)(ws + ZBF_OFF);
    float* den = (float*)(ws + DEN_OFF);
    float* s   = (float*)(ws + S_OFF);
    float* sp  = (float*)(ws + SP_OFF);

    // s/sp (256 floats) zeroed via a tiny async memset replacement:
    // norm_kernel atomically accumulates into them, so they must start at 0.
    // They sit in the same 1KB region; zero them with a 1KB store kernel is
    // overkill — reuse hipMemsetAsync once (1KB, ~negligible vs 2 previous).
    hipMemsetAsync(ws + S_OFF, 0, 1024, stream);

    hipLaunchKernelGGL(norm_kernel, dim3(256), dim3(256), 0, stream,
                       nodes, pair, zbf, s, sp, den, (float*)d_out);
    hipLaunchKernelGGL(gemm_kernel, dim3(NT * (NT + 1) / 2), dim3(256), 0, stream,
                       zbf, den);
    hipLaunchKernelGGL(final_kernel, dim3(16), dim3(256), 0, stream,
                       den, s, sp, (float*)d_out);
}